// Round 6
// baseline (325.934 us; speedup 1.0000x reference)
//
#include <hip/hip_runtime.h>
#include <hip/hip_fp8.h>
#include <cstdint>
#include <cstddef>

// Problem constants
#define BSZ   32
#define ENCN  512            // tokens per batch
#define SEQL  1024           // d_model
#define MROWS (BSZ*ENCN)     // 16384 total rows
#define N1    (3*SEQL)       // 3072 qkv features
#define K1    SEQL           // 1024
#define N2    SEQL           // 1024
#define K2    (2*SEQL)       // 2048

typedef __bf16 bf16;
typedef float  f32x4  __attribute__((ext_vector_type(4)));
typedef int    i32x4  __attribute__((ext_vector_type(4)));
typedef int    i32x8  __attribute__((ext_vector_type(8)));

__device__ __forceinline__ void gl_lds16(const void* g, void* l) {
  // global -> LDS async copy, 16B per lane. LDS dest = wave-uniform base + lane*16.
  __builtin_amdgcn_global_load_lds(
      (const __attribute__((address_space(1))) void*)(uintptr_t)g,
      (__attribute__((address_space(3))) void*)(uintptr_t)(uint32_t)(uintptr_t)l,
      16, 0, 0);
}

// pack 4 floats -> 4 fp8 e4m3 bytes (OCP on gfx950), little-endian
__device__ __forceinline__ uint32_t pk4_fp8(float a, float b, float c, float d) {
  int v = __builtin_amdgcn_cvt_pk_fp8_f32(a, b, 0, false);   // bytes 0,1
  v = __builtin_amdgcn_cvt_pk_fp8_f32(c, d, v, true);        // bytes 2,3
  return (uint32_t)v;
}
__device__ __forceinline__ uint8_t pk1_fp8(float a) {
  return (uint8_t)(__builtin_amdgcn_cvt_pk_fp8_f32(a, a, 0, false) & 0xff);
}
__device__ __forceinline__ float fp8_to_f(uint32_t b) {
  __hip_fp8_e4m3 t; t.__x = (__hip_fp8_storage_t)b; return (float)t;
}

__device__ __forceinline__ f32x4 mfma8(long a, long b, f32x4 c) {
  return __builtin_amdgcn_mfma_f32_16x16x32_fp8_fp8(a, b, c, 0, 0, 0);
}

// ---------------- weight conversion: w_in, w_out, w_m1a -> fp8 (x64) ----------------
__global__ __launch_bounds__(256) void cvt_w_kernel(const float* __restrict__ w_in,
                                                    const float* __restrict__ w_out,
                                                    const float* __restrict__ w1a,
                                                    uint8_t* __restrict__ wi8,
                                                    uint8_t* __restrict__ wo8,
                                                    uint8_t* __restrict__ w1a8) {
  int idx = blockIdx.x * 256 + threadIdx.x;   // float4 index
  const int NWIN4 = (N1 * K1) / 4;            // 786432
  const int NOUT4 = (N2 * K2) / 4;            // 524288
  const float4* src;
  uint32_t* dst;
  int j;
  if (idx < NWIN4) {
    src = (const float4*)w_in;  dst = (uint32_t*)wi8;  j = idx;
  } else if (idx < NWIN4 + NOUT4) {
    src = (const float4*)w_out; dst = (uint32_t*)wo8;  j = idx - NWIN4;
  } else {
    src = (const float4*)w1a;   dst = (uint32_t*)w1a8; j = idx - NWIN4 - NOUT4;
  }
  float4 v = src[j];
  dst[j] = pk4_fp8(v.x * 64.f, v.y * 64.f, v.z * 64.f, v.w * 64.f);
}

// ---------------- LayerNorm -> fp8 e4m3 (unit scale) ----------------
__global__ __launch_bounds__(256) void ln_kernel(const float* __restrict__ x,
                                                 const float* __restrict__ g,
                                                 const float* __restrict__ bt,
                                                 uint8_t* __restrict__ xn8) {
  int row = blockIdx.x;
  int t = threadIdx.x;
  const float4 v = ((const float4*)(x + (size_t)row * SEQL))[t];
  float s  = v.x + v.y + v.z + v.w;
  float ss = v.x*v.x + v.y*v.y + v.z*v.z + v.w*v.w;
  for (int off = 32; off; off >>= 1) {
    s  += __shfl_down(s,  off, 64);
    ss += __shfl_down(ss, off, 64);
  }
  __shared__ float red[8];
  int w = t >> 6, l = t & 63;
  if (l == 0) { red[w] = s; red[w + 4] = ss; }
  __syncthreads();
  float st  = red[0] + red[1] + red[2] + red[3];
  float sst = red[4] + red[5] + red[6] + red[7];
  float mu   = st * (1.0f / SEQL);
  float var  = sst * (1.0f / SEQL) - mu * mu;
  float rstd = rsqrtf(var + 1e-5f);
  float4 gv = ((const float4*)g)[t];
  float4 bv = ((const float4*)bt)[t];
  float y0 = (v.x - mu) * rstd * gv.x + bv.x;
  float y1 = (v.y - mu) * rstd * gv.y + bv.y;
  float y2 = (v.z - mu) * rstd * gv.z + bv.z;
  float y3 = (v.w - mu) * rstd * gv.w + bv.w;
  ((uint32_t*)(xn8 + (size_t)row * SEQL))[t] = pk4_fp8(y0, y1, y2, y3);
}

// ---------------- MX-fp8 GEMM core: C = (A*2^(SA-127)) @ (Bw*2^(SB-127))^T + bias ------
// A[M,K], Bw[N,K] fp8 e4m3. 128x128 tile, BK=128, 16x16x128 scaled MFMA.
// LDS swizzle: slot (row, c) holds global 16B chunk (row, c ^ (row&7)).
// MODE 0: out fp8 (value*64). MODE 1: out f32 = acc + bias + resid.
template <int MODE, int SA, int SB>
__device__ __forceinline__ void gemm_fp8_impl(const uint8_t* __restrict__ A,
                                              const uint8_t* __restrict__ Bw,
                                              const float* __restrict__ bias,
                                              const float* __restrict__ resid,
                                              void* __restrict__ Cout,
                                              int M, int N, int K) {
  __shared__ uint8_t Als[128 * 128];   // 16 KB
  __shared__ uint8_t Bls[128 * 128];   // 16 KB
  const int tid = threadIdx.x;
  const int w = tid >> 6, l = tid & 63;
  const int wm = w & 1, wn = w >> 1;
  const int q = l >> 4, li = l & 15;
  const int m0 = blockIdx.x * 128;
  const int n0 = blockIdx.y * 128;

  const int srow = tid >> 3;                          // 0..31 within issue
  const int scol = ((tid & 7) ^ (srow & 7)) << 4;     // source byte col within BK

  const int c0 = ((2 * q)     ^ (li & 7)) << 4;
  const int c1 = ((2 * q + 1) ^ (li & 7)) << 4;

  f32x4 acc[4][4] = {};

  for (int k0 = 0; k0 < K; k0 += 128) {
#pragma unroll
    for (int is = 0; is < 4; is++) {
      gl_lds16(A  + (size_t)(m0 + is * 32 + srow) * K + k0 + scol,
               (char*)Als + is * 4096 + w * 1024);
      gl_lds16(Bw + (size_t)(n0 + is * 32 + srow) * K + k0 + scol,
               (char*)Bls + is * 4096 + w * 1024);
    }
    __syncthreads();
    i32x8 af[4], bfg[4];
#pragma unroll
    for (int i = 0; i < 4; i++) {
      int r = wm * 64 + i * 16 + li;
      i32x4 lo = *(const i32x4*)&Als[r * 128 + c0];
      i32x4 hi = *(const i32x4*)&Als[r * 128 + c1];
      af[i] = i32x8{lo[0], lo[1], lo[2], lo[3], hi[0], hi[1], hi[2], hi[3]};
    }
#pragma unroll
    for (int j = 0; j < 4; j++) {
      int r = wn * 64 + j * 16 + li;
      i32x4 lo = *(const i32x4*)&Bls[r * 128 + c0];
      i32x4 hi = *(const i32x4*)&Bls[r * 128 + c1];
      bfg[j] = i32x8{lo[0], lo[1], lo[2], lo[3], hi[0], hi[1], hi[2], hi[3]};
    }
#pragma unroll
    for (int i = 0; i < 4; i++)
#pragma unroll
      for (int j = 0; j < 4; j++)
        acc[i][j] = __builtin_amdgcn_mfma_scale_f32_16x16x128_f8f6f4(
            af[i], bfg[j], acc[i][j], 0 /*A fmt fp8*/, 0 /*B fmt fp8*/,
            0, SA, 0, SB);
    __syncthreads();
  }

#pragma unroll
  for (int i = 0; i < 4; i++)
#pragma unroll
    for (int j = 0; j < 4; j++) {
      int col = n0 + wn * 64 + j * 16 + li;
      float bv = bias[col];
#pragma unroll
      for (int r = 0; r < 4; r++) {
        int row = m0 + wm * 64 + i * 16 + q * 4 + r;
        float v = acc[i][j][r] + bv;
        if (MODE == 0) {
          ((uint8_t*)Cout)[(size_t)row * N + col] = pk1_fp8(v * 64.f);
        } else {
          ((float*)Cout)[(size_t)row * N + col] = v + resid[(size_t)row * N + col];
        }
      }
    }
}

__global__ __launch_bounds__(256) void gemm_qkv(const uint8_t* __restrict__ A,
                                                const uint8_t* __restrict__ Bw,
                                                const float* __restrict__ bias,
                                                uint8_t* __restrict__ Cout) {
  gemm_fp8_impl<0, 127, 121>(A, Bw, bias, nullptr, Cout, MROWS, N1, K1);
}
__global__ __launch_bounds__(256) void gemm_out(const uint8_t* __restrict__ A,
                                                const uint8_t* __restrict__ Bw,
                                                const float* __restrict__ bias,
                                                const float* __restrict__ resid,
                                                float* __restrict__ Cout) {
  gemm_fp8_impl<1, 113, 121>(A, Bw, bias, resid, Cout, MROWS, N2, K2);
}

// ---------------- mlp1 + mlp2-partial on fp8 qkv: block per (tensor, bh, quarter) ------
// qkv8 values are true*64; w1a8 is true*64.
//   A1[T][bh*512 + quarter*128 + lc] = relu(chunk @ W1a^T + b1a) . w1b + b1b   (true)
//   A2p[...][d] = 64 * sum over 16 rows of t[n,d]*w2[n]                        (x64)
__global__ __launch_bounds__(256) void mlp12_kernel(const uint8_t* __restrict__ qkv8,
                                                    const uint8_t* __restrict__ w1a8,
                                                    const float* __restrict__ b1a,
                                                    const float* __restrict__ w1b,
                                                    const float* __restrict__ b1b,
                                                    const float* __restrict__ w2,
                                                    float* __restrict__ A1q,
                                                    float* __restrict__ A1k,
                                                    float* __restrict__ A2p) {
  __shared__ float red1[2][128];
  __shared__ float redm[16][128];
  __shared__ float w2s[128];
  const int bid = blockIdx.x;
  const int T = bid >> 10;                 // 0=q, 1=k
  const int rem = bid & 1023;
  const int bh = rem >> 2, quarter = rem & 3;
  const int tid = threadIdx.x;
  const int w = tid >> 6, l = tid & 63;
  const int wm = w & 1, wn = w >> 1;
  const int q = l >> 4, li = l & 15;
  const int R0 = bh * 64 + quarter * 16;   // first global qkv row
  const uint8_t* rbase = qkv8 + (size_t)R0 * N1 + T * 1024;

  if (tid < 128) w2s[tid] = w2[quarter * 128 + tid];

  // W1a fragments in registers: B[k][n] = w1a[n][k], 8 fp8 bytes each
  long bfrag[4][4];
  float b1av[4], w1bv[4];
#pragma unroll
  for (int j = 0; j < 4; j++) {
    int n = wn * 64 + j * 16 + li;
#pragma unroll
    for (int kq = 0; kq < 4; kq++)
      bfrag[kq][j] = *(const long*)&w1a8[n * 128 + kq * 32 + q * 8];
    b1av[j] = b1a[n];
    w1bv[j] = w1b[n];
  }

  // ---- mlp1 MFMA over 128 chunks (acc = true*4096) ----
  f32x4 acc[4][4] = {};
#pragma unroll
  for (int kq = 0; kq < 4; kq++) {
#pragma unroll
    for (int i = 0; i < 4; i++) {
      int lc = wm * 64 + i * 16 + li;      // local chunk 0..127
      long af = *(const long*)(rbase + (size_t)(lc >> 3) * N1
                               + (lc & 7) * 128 + kq * 32 + q * 8);
#pragma unroll
      for (int j = 0; j < 4; j++)
        acc[i][j] = mfma8(af, bfrag[kq][j], acc[i][j]);
    }
  }
  const float inv4096 = 1.0f / 4096.0f;
#pragma unroll
  for (int i = 0; i < 4; i++)
#pragma unroll
    for (int r = 0; r < 4; r++) {
      float s = 0.f;
#pragma unroll
      for (int j = 0; j < 4; j++)
        s += fmaxf(acc[i][j][r] * inv4096 + b1av[j], 0.f) * w1bv[j];
      for (int off = 1; off < 16; off <<= 1) s += __shfl_xor(s, off, 64);
      if (li == 0) red1[wn][wm * 64 + i * 16 + q * 4 + r] = s;
    }
  __syncthreads();
  if (tid < 128) {
    float v = red1[0][tid] + red1[1][tid] + b1b[0];
    (T ? A1k : A1q)[bh * 512 + quarter * 128 + tid] = v;
  }

  // ---- mlp2 partial over the same 16 rows (L1/L2-hot), values x64 ----
  const int rg = tid >> 4, dg = tid & 15;  // row 0..15, d-group of 8
  const uint8_t* arow = rbase + (size_t)rg * N1 + dg * 8;
  float a8[8] = {0, 0, 0, 0, 0, 0, 0, 0};
#pragma unroll
  for (int cc = 0; cc < 8; cc++) {
    uint64_t vb = *(const uint64_t*)(arow + cc * 128);
    float wgt = w2s[rg * 8 + cc];
#pragma unroll
    for (int e = 0; e < 8; e++)
      a8[e] += fp8_to_f((uint32_t)(vb >> (8 * e)) & 0xff) * wgt;
  }
#pragma unroll
  for (int e = 0; e < 8; e++) redm[rg][dg * 8 + e] = a8[e];
  __syncthreads();
  if (tid < 128) {
    float s = 0.f;
#pragma unroll
    for (int rg2 = 0; rg2 < 16; rg2++) s += redm[rg2][tid];
    A2p[(((size_t)T * 256 + bh) * 4 + quarter) * 128 + tid] = s;
  }
}

// ---------------- A2 combine: sum 4 quarter-partials (x64) -> /64 + b2, relu -----------
__global__ __launch_bounds__(256) void a2c_kernel(const float* __restrict__ A2p,
                                                  const float* __restrict__ b2,
                                                  float* __restrict__ A2q,
                                                  float* __restrict__ A2k) {
  int idx = blockIdx.x * 256 + threadIdx.x;     // 65536 total
  int t = idx >> 15, r = idx & 32767;           // r = bh*128 + d
  int bh = r >> 7, d = r & 127;
  const float* p = A2p + ((size_t)t * 256 + bh) * 512 + d;
  float s = (p[0] + p[128] + p[256] + p[384]) * (1.0f / 64.0f) + b2[0];
  (t ? A2k : A2q)[r] = fmaxf(s, 0.f);
}

// ---------------- scale & concat -> fp8 Y ----------------
// Y = A1*A2*v64 where v64 = fp8-decode(v plane) = 64*v; this equals true*2^14.
__global__ __launch_bounds__(256) void scale_kernel(const uint8_t* __restrict__ qkv8,
                                                    const float* __restrict__ A1q,
                                                    const float* __restrict__ A1k,
                                                    const float* __restrict__ A2q,
                                                    const float* __restrict__ A2k,
                                                    uint8_t* __restrict__ Y) {
  size_t idx = ((size_t)blockIdx.x * 256 + threadIdx.x) * 8;  // over B*524288 elems
  int b = (int)(idx >> 19);
  int f = (int)(idx & 524287);
  int chunk = f >> 7;
  float a1q = A1q[b * 4096 + chunk];
  float a1k = A1k[b * 4096 + chunk];
  int a2i = b * 1024 + ((f >> 16) << 7) + (f & 127);
  float4 k0 = *(const float4*)&A2k[a2i];
  float4 k1 = *(const float4*)&A2k[a2i + 4];
  float4 q0 = *(const float4*)&A2q[a2i];
  float4 q1 = *(const float4*)&A2q[a2i + 4];
  int row = b * 512 + (f >> 10);
  int col = f & 1023;
  uint64_t vb = *(const uint64_t*)(qkv8 + (size_t)row * N1 + 2048 + col);
  float kk[8] = { k0.x, k0.y, k0.z, k0.w, k1.x, k1.y, k1.z, k1.w };
  float qq[8] = { q0.x, q0.y, q0.z, q0.w, q1.x, q1.y, q1.z, q1.w };
  float y1[8], y2[8];
#pragma unroll
  for (int e = 0; e < 8; e++) {
    float v64 = fp8_to_f((uint32_t)(vb >> (8 * e)) & 0xff);
    y1[e] = a1q * kk[e] * v64;
    y2[e] = a1k * qq[e] * v64;
  }
  uint8_t* yr = Y + (size_t)row * K2;
  ((uint32_t*)(yr + col))[0] = pk4_fp8(y1[0], y1[1], y1[2], y1[3]);
  ((uint32_t*)(yr + col))[1] = pk4_fp8(y1[4], y1[5], y1[6], y1[7]);
  ((uint32_t*)(yr + 1024 + col))[0] = pk4_fp8(y2[0], y2[1], y2[2], y2[3]);
  ((uint32_t*)(yr + 1024 + col))[1] = pk4_fp8(y2[4], y2[5], y2[6], y2[7]);
}

extern "C" void kernel_launch(void* const* d_in, const int* in_sizes, int n_in,
                              void* d_out, int out_size, void* d_ws, size_t ws_size,
                              hipStream_t stream) {
  const float* x     = (const float*)d_in[0];
  const float* ln_g  = (const float*)d_in[1];
  const float* ln_b  = (const float*)d_in[2];
  const float* w_in  = (const float*)d_in[3];
  const float* b_in  = (const float*)d_in[4];
  const float* w1a   = (const float*)d_in[5];
  const float* b1a   = (const float*)d_in[6];
  const float* w1b   = (const float*)d_in[7];
  const float* b1b   = (const float*)d_in[8];
  const float* w2    = (const float*)d_in[9];
  const float* b2    = (const float*)d_in[10];
  const float* w_out = (const float*)d_in[11];
  const float* b_out = (const float*)d_in[12];
  float* out = (float*)d_out;
  char* ws = (char*)d_ws;

  // workspace layout (bytes). xn8 and Y8 alias: xn8 is dead before scale writes Y8.
  uint8_t* xn8  = (uint8_t*)(ws);                   //  16,777,216 (phase 1)
  uint8_t* Y8   = (uint8_t*)(ws);                   //  33,554,432 (phase 2+)
  uint8_t* qkv8 = (uint8_t*)(ws + 33554432);        //  50,331,648
  uint8_t* wi8  = (uint8_t*)(ws + 83886080);        //   3,145,728
  uint8_t* wo8  = (uint8_t*)(ws + 87031808);        //   2,097,152
  uint8_t* w1a8 = (uint8_t*)(ws + 89128960);        //      16,384
  float*   A1q  = (float*)  (ws + 89145344);        //     524,288
  float*   A1k  = (float*)  (ws + 89669632);        //     524,288
  float*   A2p  = (float*)  (ws + 90193920);        //   1,048,576
  float*   A2q  = (float*)  (ws + 91242496);        //     131,072
  float*   A2k  = (float*)  (ws + 91373568);        //     131,072

  cvt_w_kernel<<<5136, 256, 0, stream>>>(w_in, w_out, w1a, wi8, wo8, w1a8);
  ln_kernel<<<MROWS, 256, 0, stream>>>(x, ln_g, ln_b, xn8);
  gemm_qkv<<<dim3(MROWS / 128, N1 / 128), 256, 0, stream>>>(xn8, wi8, b_in, qkv8);
  mlp12_kernel<<<2048, 256, 0, stream>>>(qkv8, w1a8, b1a, w1b, b1b, w2, A1q, A1k, A2p);
  a2c_kernel<<<256, 256, 0, stream>>>(A2p, b2, A2q, A2k);
  scale_kernel<<<8192, 256, 0, stream>>>(qkv8, A1q, A1k, A2q, A2k, Y8);
  gemm_out<<<dim3(MROWS / 128, N2 / 128), 256, 0, stream>>>(Y8, wo8, b_out, x, out);
}

// Round 7
// 312.919 us; speedup vs baseline: 1.0416x; 1.0416x over previous
//
#include <hip/hip_runtime.h>
#include <hip/hip_fp8.h>
#include <cstdint>
#include <cstddef>

// Problem constants
#define BSZ   32
#define ENCN  512            // tokens per batch
#define SEQL  1024           // d_model
#define MROWS (BSZ*ENCN)     // 16384 total rows
#define N1    (3*SEQL)       // 3072 qkv features
#define K1    SEQL           // 1024
#define N2    SEQL           // 1024
#define K2    (2*SEQL)       // 2048

typedef __bf16 bf16;
typedef float  f32x4  __attribute__((ext_vector_type(4)));
typedef int    i32x4  __attribute__((ext_vector_type(4)));
typedef int    i32x8  __attribute__((ext_vector_type(8)));
typedef long   i64x2  __attribute__((ext_vector_type(2)));

__device__ __forceinline__ void gl_lds16(const void* g, void* l) {
  // global -> LDS async copy, 16B per lane. LDS dest = wave-uniform base + lane*16.
  __builtin_amdgcn_global_load_lds(
      (const __attribute__((address_space(1))) void*)(uintptr_t)g,
      (__attribute__((address_space(3))) void*)(uintptr_t)(uint32_t)(uintptr_t)l,
      16, 0, 0);
}

// pack 4 floats -> 4 fp8 e4m3 bytes (OCP on gfx950), little-endian
__device__ __forceinline__ uint32_t pk4_fp8(float a, float b, float c, float d) {
  int v = __builtin_amdgcn_cvt_pk_fp8_f32(a, b, 0, false);   // bytes 0,1
  v = __builtin_amdgcn_cvt_pk_fp8_f32(c, d, v, true);        // bytes 2,3
  return (uint32_t)v;
}
__device__ __forceinline__ float fp8_to_f(uint32_t b) {
  __hip_fp8_e4m3 t; t.__x = (__hip_fp8_storage_t)b; return (float)t;
}

__device__ __forceinline__ f32x4 mfma8(long a, long b, f32x4 c) {
  return __builtin_amdgcn_mfma_f32_16x16x32_fp8_fp8(a, b, c, 0, 0, 0);
}

// ---------------- weight conversion: w_in, w_out, w_m1a -> fp8 (x64) ----------------
__global__ __launch_bounds__(256) void cvt_w_kernel(const float* __restrict__ w_in,
                                                    const float* __restrict__ w_out,
                                                    const float* __restrict__ w1a,
                                                    uint8_t* __restrict__ wi8,
                                                    uint8_t* __restrict__ wo8,
                                                    uint8_t* __restrict__ w1a8) {
  int idx = blockIdx.x * 256 + threadIdx.x;   // float4 index
  const int NWIN4 = (N1 * K1) / 4;            // 786432
  const int NOUT4 = (N2 * K2) / 4;            // 524288
  const float4* src;
  uint32_t* dst;
  int j;
  if (idx < NWIN4) {
    src = (const float4*)w_in;  dst = (uint32_t*)wi8;  j = idx;
  } else if (idx < NWIN4 + NOUT4) {
    src = (const float4*)w_out; dst = (uint32_t*)wo8;  j = idx - NWIN4;
  } else {
    src = (const float4*)w1a;   dst = (uint32_t*)w1a8; j = idx - NWIN4 - NOUT4;
  }
  float4 v = src[j];
  dst[j] = pk4_fp8(v.x * 64.f, v.y * 64.f, v.z * 64.f, v.w * 64.f);
}

// ---------------- LayerNorm -> fp8 e4m3 (unit scale) ----------------
__global__ __launch_bounds__(256) void ln_kernel(const float* __restrict__ x,
                                                 const float* __restrict__ g,
                                                 const float* __restrict__ bt,
                                                 uint8_t* __restrict__ xn8) {
  int row = blockIdx.x;
  int t = threadIdx.x;
  const float4 v = ((const float4*)(x + (size_t)row * SEQL))[t];
  float s  = v.x + v.y + v.z + v.w;
  float ss = v.x*v.x + v.y*v.y + v.z*v.z + v.w*v.w;
  for (int off = 32; off; off >>= 1) {
    s  += __shfl_down(s,  off, 64);
    ss += __shfl_down(ss, off, 64);
  }
  __shared__ float red[8];
  int w = t >> 6, l = t & 63;
  if (l == 0) { red[w] = s; red[w + 4] = ss; }
  __syncthreads();
  float st  = red[0] + red[1] + red[2] + red[3];
  float sst = red[4] + red[5] + red[6] + red[7];
  float mu   = st * (1.0f / SEQL);
  float var  = sst * (1.0f / SEQL) - mu * mu;
  float rstd = rsqrtf(var + 1e-5f);
  float4 gv = ((const float4*)g)[t];
  float4 bv = ((const float4*)bt)[t];
  float y0 = (v.x - mu) * rstd * gv.x + bv.x;
  float y1 = (v.y - mu) * rstd * gv.y + bv.y;
  float y2 = (v.z - mu) * rstd * gv.z + bv.z;
  float y3 = (v.w - mu) * rstd * gv.w + bv.w;
  ((uint32_t*)(xn8 + (size_t)row * SEQL))[t] = pk4_fp8(y0, y1, y2, y3);
}

// ---------------- MX-fp8 GEMM core: C = (A*2^(SA-127)) @ (Bw*2^(SB-127))^T + bias ------
// A[M,K], Bw[N,K] fp8 e4m3. 128x128 tile, BK=128, 16x16x128 scaled MFMA.
// LDS swizzle: slot (row, c) holds global 16B chunk (row, c ^ (row&7)).
// Epilogue: per-wave LDS transpose (stride 68 floats) -> vectorized stores.
// MODE 0: out fp8 (value*64), dwordx4 stores. MODE 1: out f32 = acc+bias+resid, float4.
template <int MODE, int SA, int SB>
__device__ __forceinline__ void gemm_fp8_impl(const uint8_t* __restrict__ A,
                                              const uint8_t* __restrict__ Bw,
                                              const float* __restrict__ bias,
                                              const float* __restrict__ resid,
                                              void* __restrict__ Cout,
                                              int M, int N, int K) {
  __shared__ __align__(16) uint8_t smem[32768];
  uint8_t* Als = smem;              // 16 KB
  uint8_t* Bls = smem + 16384;      // 16 KB
  const int tid = threadIdx.x;
  const int w = tid >> 6, l = tid & 63;
  const int wm = w & 1, wn = w >> 1;
  const int q = l >> 4, li = l & 15;
  const int m0 = blockIdx.x * 128;
  const int n0 = blockIdx.y * 128;

  const int srow = tid >> 3;                          // 0..31 within issue
  const int scol = ((tid & 7) ^ (srow & 7)) << 4;     // source byte col within BK

  const int c0 = ((2 * q)     ^ (li & 7)) << 4;
  const int c1 = ((2 * q + 1) ^ (li & 7)) << 4;

  f32x4 acc[4][4] = {};

  for (int k0 = 0; k0 < K; k0 += 128) {
#pragma unroll
    for (int is = 0; is < 4; is++) {
      gl_lds16(A  + (size_t)(m0 + is * 32 + srow) * K + k0 + scol,
               (char*)Als + is * 4096 + w * 1024);
      gl_lds16(Bw + (size_t)(n0 + is * 32 + srow) * K + k0 + scol,
               (char*)Bls + is * 4096 + w * 1024);
    }
    __syncthreads();
    i32x8 af[4], bfg[4];
#pragma unroll
    for (int i = 0; i < 4; i++) {
      int r = wm * 64 + i * 16 + li;
      i32x4 lo = *(const i32x4*)&Als[r * 128 + c0];
      i32x4 hi = *(const i32x4*)&Als[r * 128 + c1];
      af[i] = i32x8{lo[0], lo[1], lo[2], lo[3], hi[0], hi[1], hi[2], hi[3]};
    }
#pragma unroll
    for (int j = 0; j < 4; j++) {
      int r = wn * 64 + j * 16 + li;
      i32x4 lo = *(const i32x4*)&Bls[r * 128 + c0];
      i32x4 hi = *(const i32x4*)&Bls[r * 128 + c1];
      bfg[j] = i32x8{lo[0], lo[1], lo[2], lo[3], hi[0], hi[1], hi[2], hi[3]};
    }
#pragma unroll
    for (int i = 0; i < 4; i++)
#pragma unroll
      for (int j = 0; j < 4; j++)
        acc[i][j] = __builtin_amdgcn_mfma_scale_f32_16x16x128_f8f6f4(
            af[i], bfg[j], acc[i][j], 0 /*A fmt fp8*/, 0 /*B fmt fp8*/,
            0, SA, 0, SB);
    __syncthreads();
  }

  // ---- epilogue: per-wave 16x64 f32 transpose buffer, row stride 68 floats ----
  float* Wf = (float*)smem + w * 1088;   // 16*68 floats per wave (17408 B total)
#pragma unroll
  for (int i = 0; i < 4; i++) {
#pragma unroll
    for (int j = 0; j < 4; j++)
#pragma unroll
      for (int r = 0; r < 4; r++)
        Wf[(q * 4 + r) * 68 + j * 16 + li] = acc[i][j][r];
    __syncthreads();
    const int row = m0 + wm * 64 + i * 16 + li;
    if (MODE == 0) {
      const int cb = n0 + wn * 64 + q * 16;
      f32x4 v0 = *(const f32x4*)&Wf[li * 68 + q * 16 + 0];
      f32x4 v1 = *(const f32x4*)&Wf[li * 68 + q * 16 + 4];
      f32x4 v2 = *(const f32x4*)&Wf[li * 68 + q * 16 + 8];
      f32x4 v3 = *(const f32x4*)&Wf[li * 68 + q * 16 + 12];
      float4 b0 = *(const float4*)&bias[cb + 0];
      float4 b1 = *(const float4*)&bias[cb + 4];
      float4 b2 = *(const float4*)&bias[cb + 8];
      float4 b3 = *(const float4*)&bias[cb + 12];
      i32x4 d;
      d[0] = (int)pk4_fp8((v0[0]+b0.x)*64.f, (v0[1]+b0.y)*64.f,
                          (v0[2]+b0.z)*64.f, (v0[3]+b0.w)*64.f);
      d[1] = (int)pk4_fp8((v1[0]+b1.x)*64.f, (v1[1]+b1.y)*64.f,
                          (v1[2]+b1.z)*64.f, (v1[3]+b1.w)*64.f);
      d[2] = (int)pk4_fp8((v2[0]+b2.x)*64.f, (v2[1]+b2.y)*64.f,
                          (v2[2]+b2.z)*64.f, (v2[3]+b2.w)*64.f);
      d[3] = (int)pk4_fp8((v3[0]+b3.x)*64.f, (v3[1]+b3.y)*64.f,
                          (v3[2]+b3.z)*64.f, (v3[3]+b3.w)*64.f);
      *(i32x4*)((uint8_t*)Cout + (size_t)row * N + cb) = d;
    } else {
#pragma unroll
      for (int c4 = 0; c4 < 4; c4++) {
        const int cb = n0 + wn * 64 + c4 * 16 + q * 4;
        f32x4 vv = *(const f32x4*)&Wf[li * 68 + c4 * 16 + q * 4];
        float4 bb = *(const float4*)&bias[cb];
        float4 rr = *(const float4*)&resid[(size_t)row * N + cb];
        float4 o = { vv[0] + bb.x + rr.x, vv[1] + bb.y + rr.y,
                     vv[2] + bb.z + rr.z, vv[3] + bb.w + rr.w };
        *(float4*)((float*)Cout + (size_t)row * N + cb) = o;
      }
    }
    __syncthreads();
  }
}

__global__ __launch_bounds__(256) void gemm_qkv(const uint8_t* __restrict__ A,
                                                const uint8_t* __restrict__ Bw,
                                                const float* __restrict__ bias,
                                                uint8_t* __restrict__ Cout) {
  gemm_fp8_impl<0, 127, 121>(A, Bw, bias, nullptr, Cout, MROWS, N1, K1);
}
__global__ __launch_bounds__(256) void gemm_out(const uint8_t* __restrict__ A,
                                                const uint8_t* __restrict__ Bw,
                                                const float* __restrict__ bias,
                                                const float* __restrict__ resid,
                                                float* __restrict__ Cout) {
  gemm_fp8_impl<1, 113, 121>(A, Bw, bias, resid, Cout, MROWS, N2, K2);
}

// ---------------- mlp1 + mlp2-partial on fp8 qkv: block per (tensor, bh, quarter) ------
// qkv8 values are true*64; w1a8 is true*64.
// K-permutation: MFMA #kq, lane q, byte j <-> global k = q*32 + kq*8 + j (A and B agree).
__global__ __launch_bounds__(256) void mlp12_kernel(const uint8_t* __restrict__ qkv8,
                                                    const uint8_t* __restrict__ w1a8,
                                                    const float* __restrict__ b1a,
                                                    const float* __restrict__ w1b,
                                                    const float* __restrict__ b1b,
                                                    const float* __restrict__ w2,
                                                    float* __restrict__ A1q,
                                                    float* __restrict__ A1k,
                                                    float* __restrict__ A2p) {
  __shared__ float red1[2][128];
  __shared__ float redm[16][128];
  __shared__ float w2s[128];
  const int bid = blockIdx.x;
  const int T = bid >> 10;                 // 0=q, 1=k
  const int rem = bid & 1023;
  const int bh = rem >> 2, quarter = rem & 3;
  const int tid = threadIdx.x;
  const int w = tid >> 6, l = tid & 63;
  const int wm = w & 1, wn = w >> 1;
  const int q = l >> 4, li = l & 15;
  const int R0 = bh * 64 + quarter * 16;   // first global qkv row
  const uint8_t* rbase = qkv8 + (size_t)R0 * N1 + T * 1024;

  if (tid < 128) w2s[tid] = w2[quarter * 128 + tid];

  // W1a fragments: bfrag[kq][j] holds w1a[n][q*32 + kq*8 .. +8]
  long bfrag[4][4];
  float b1av[4], w1bv[4];
#pragma unroll
  for (int j = 0; j < 4; j++) {
    int n = wn * 64 + j * 16 + li;
#pragma unroll
    for (int kq = 0; kq < 4; kq++)
      bfrag[kq][j] = *(const long*)&w1a8[n * 128 + q * 32 + kq * 8];
    b1av[j] = b1a[n];
    w1bv[j] = w1b[n];
  }

  // ---- mlp1 MFMA over 128 chunks (acc = true*4096); contiguous 32-B A loads ----
  f32x4 acc[4][4] = {};
#pragma unroll
  for (int i = 0; i < 4; i++) {
    int lc = wm * 64 + i * 16 + li;        // local chunk 0..127
    const uint8_t* abase = rbase + (size_t)(lc >> 3) * N1 + (lc & 7) * 128 + q * 32;
    i64x2 p0 = *(const i64x2*)abase;
    i64x2 p1 = *(const i64x2*)(abase + 16);
    long f[4] = { p0[0], p0[1], p1[0], p1[1] };
#pragma unroll
    for (int kq = 0; kq < 4; kq++)
#pragma unroll
      for (int j = 0; j < 4; j++)
        acc[i][j] = mfma8(f[kq], bfrag[kq][j], acc[i][j]);
  }
  const float inv4096 = 1.0f / 4096.0f;
#pragma unroll
  for (int i = 0; i < 4; i++)
#pragma unroll
    for (int r = 0; r < 4; r++) {
      float s = 0.f;
#pragma unroll
      for (int j = 0; j < 4; j++)
        s += fmaxf(acc[i][j][r] * inv4096 + b1av[j], 0.f) * w1bv[j];
      for (int off = 1; off < 16; off <<= 1) s += __shfl_xor(s, off, 64);
      if (li == 0) red1[wn][wm * 64 + i * 16 + q * 4 + r] = s;
    }
  __syncthreads();
  if (tid < 128) {
    float v = red1[0][tid] + red1[1][tid] + b1b[0];
    (T ? A1k : A1q)[bh * 512 + quarter * 128 + tid] = v;
  }

  // ---- mlp2 partial over the same 16 rows (L1/L2-hot), values x64 ----
  const int rg = tid >> 4, dg = tid & 15;  // row 0..15, d-group of 8
  const uint8_t* arow = rbase + (size_t)rg * N1 + dg * 8;
  float a8[8] = {0, 0, 0, 0, 0, 0, 0, 0};
#pragma unroll
  for (int cc = 0; cc < 8; cc++) {
    uint64_t vb = *(const uint64_t*)(arow + cc * 128);
    float wgt = w2s[rg * 8 + cc];
#pragma unroll
    for (int e = 0; e < 8; e++)
      a8[e] += fp8_to_f((uint32_t)(vb >> (8 * e)) & 0xff) * wgt;
  }
#pragma unroll
  for (int e = 0; e < 8; e++) redm[rg][dg * 8 + e] = a8[e];
  __syncthreads();
  if (tid < 128) {
    float s = 0.f;
#pragma unroll
    for (int rg2 = 0; rg2 < 16; rg2++) s += redm[rg2][tid];
    A2p[(((size_t)T * 256 + bh) * 4 + quarter) * 128 + tid] = s;
  }
}

// ---------------- A2 combine: sum 4 quarter-partials (x64) -> /64 + b2, relu -----------
__global__ __launch_bounds__(256) void a2c_kernel(const float* __restrict__ A2p,
                                                  const float* __restrict__ b2,
                                                  float* __restrict__ A2q,
                                                  float* __restrict__ A2k) {
  int idx = blockIdx.x * 256 + threadIdx.x;     // 65536 total
  int t = idx >> 15, r = idx & 32767;           // r = bh*128 + d
  int bh = r >> 7, d = r & 127;
  const float* p = A2p + ((size_t)t * 256 + bh) * 512 + d;
  float s = (p[0] + p[128] + p[256] + p[384]) * (1.0f / 64.0f) + b2[0];
  (t ? A2k : A2q)[r] = fmaxf(s, 0.f);
}

// ---------------- scale & concat -> fp8 Y ----------------
// Y = A1*A2*v64 where v64 = fp8-decode(v plane) = 64*v; this equals true*2^14.
__global__ __launch_bounds__(256) void scale_kernel(const uint8_t* __restrict__ qkv8,
                                                    const float* __restrict__ A1q,
                                                    const float* __restrict__ A1k,
                                                    const float* __restrict__ A2q,
                                                    const float* __restrict__ A2k,
                                                    uint8_t* __restrict__ Y) {
  size_t idx = ((size_t)blockIdx.x * 256 + threadIdx.x) * 8;  // over B*524288 elems
  int b = (int)(idx >> 19);
  int f = (int)(idx & 524287);
  int chunk = f >> 7;
  float a1q = A1q[b * 4096 + chunk];
  float a1k = A1k[b * 4096 + chunk];
  int a2i = b * 1024 + ((f >> 16) << 7) + (f & 127);
  float4 k0 = *(const float4*)&A2k[a2i];
  float4 k1 = *(const float4*)&A2k[a2i + 4];
  float4 q0 = *(const float4*)&A2q[a2i];
  float4 q1 = *(const float4*)&A2q[a2i + 4];
  int row = b * 512 + (f >> 10);
  int col = f & 1023;
  uint64_t vb = *(const uint64_t*)(qkv8 + (size_t)row * N1 + 2048 + col);
  float kk[8] = { k0.x, k0.y, k0.z, k0.w, k1.x, k1.y, k1.z, k1.w };
  float qq[8] = { q0.x, q0.y, q0.z, q0.w, q1.x, q1.y, q1.z, q1.w };
  float y1[8], y2[8];
#pragma unroll
  for (int e = 0; e < 8; e++) {
    float v64 = fp8_to_f((uint32_t)(vb >> (8 * e)) & 0xff);
    y1[e] = a1q * kk[e] * v64;
    y2[e] = a1k * qq[e] * v64;
  }
  uint8_t* yr = Y + (size_t)row * K2;
  ((uint32_t*)(yr + col))[0] = pk4_fp8(y1[0], y1[1], y1[2], y1[3]);
  ((uint32_t*)(yr + col))[1] = pk4_fp8(y1[4], y1[5], y1[6], y1[7]);
  ((uint32_t*)(yr + 1024 + col))[0] = pk4_fp8(y2[0], y2[1], y2[2], y2[3]);
  ((uint32_t*)(yr + 1024 + col))[1] = pk4_fp8(y2[4], y2[5], y2[6], y2[7]);
}

extern "C" void kernel_launch(void* const* d_in, const int* in_sizes, int n_in,
                              void* d_out, int out_size, void* d_ws, size_t ws_size,
                              hipStream_t stream) {
  const float* x     = (const float*)d_in[0];
  const float* ln_g  = (const float*)d_in[1];
  const float* ln_b  = (const float*)d_in[2];
  const float* w_in  = (const float*)d_in[3];
  const float* b_in  = (const float*)d_in[4];
  const float* w1a   = (const float*)d_in[5];
  const float* b1a   = (const float*)d_in[6];
  const float* w1b   = (const float*)d_in[7];
  const float* b1b   = (const float*)d_in[8];
  const float* w2    = (const float*)d_in[9];
  const float* b2    = (const float*)d_in[10];
  const float* w_out = (const float*)d_in[11];
  const float* b_out = (const float*)d_in[12];
  float* out = (float*)d_out;
  char* ws = (char*)d_ws;

  // workspace layout (bytes). xn8 and Y8 alias: xn8 is dead before scale writes Y8.
  uint8_t* xn8  = (uint8_t*)(ws);                   //  16,777,216 (phase 1)
  uint8_t* Y8   = (uint8_t*)(ws);                   //  33,554,432 (phase 2+)
  uint8_t* qkv8 = (uint8_t*)(ws + 33554432);        //  50,331,648
  uint8_t* wi8  = (uint8_t*)(ws + 83886080);        //   3,145,728
  uint8_t* wo8  = (uint8_t*)(ws + 87031808);        //   2,097,152
  uint8_t* w1a8 = (uint8_t*)(ws + 89128960);        //      16,384
  float*   A1q  = (float*)  (ws + 89145344);        //     524,288
  float*   A1k  = (float*)  (ws + 89669632);        //     524,288
  float*   A2p  = (float*)  (ws + 90193920);        //   1,048,576
  float*   A2q  = (float*)  (ws + 91242496);        //     131,072
  float*   A2k  = (float*)  (ws + 91373568);        //     131,072

  cvt_w_kernel<<<5136, 256, 0, stream>>>(w_in, w_out, w1a, wi8, wo8, w1a8);
  ln_kernel<<<MROWS, 256, 0, stream>>>(x, ln_g, ln_b, xn8);
  gemm_qkv<<<dim3(MROWS / 128, N1 / 128), 256, 0, stream>>>(xn8, wi8, b_in, qkv8);
  mlp12_kernel<<<2048, 256, 0, stream>>>(qkv8, w1a8, b1a, w1b, b1b, w2, A1q, A1k, A2p);
  a2c_kernel<<<256, 256, 0, stream>>>(A2p, b2, A2q, A2k);
  scale_kernel<<<8192, 256, 0, stream>>>(qkv8, A1q, A1k, A2q, A2k, Y8);
  gemm_out<<<dim3(MROWS / 128, N2 / 128), 256, 0, stream>>>(Y8, wo8, b_out, x, out);
}